// Round 7
// baseline (277.028 us; speedup 1.0000x reference)
//
#include <hip/hip_runtime.h>
#include <hip/hip_bf16.h>
#include <stdint.h>

typedef __attribute__((ext_vector_type(8))) short bf16x8;
typedef __attribute__((ext_vector_type(4))) float f32x4;
typedef __attribute__((ext_vector_type(4))) unsigned short u16x4;

#define T_SEQ 2048
#define HID_D 2880
#define KPAD 2944              // 2880 padded to 46*64
#define NH 64
#define NKV 8
#define HD 64
#define QKV_N 5120
#define ATT_N 4096
#define WIN 128
#define RSCALE 0.125f
#define MSCALE 1.3465735903f

__device__ __forceinline__ unsigned short f2bf(float f) {
  union { float f; unsigned u; } v; v.f = f;
  unsigned r = v.u + 0x7fffu + ((v.u >> 16) & 1u);
  return (unsigned short)(r >> 16);
}

__device__ __forceinline__ float yarn_invf(int dp) {
  float pw = (float)dp * (1.0f / 32.0f);
  float extrap = expf(-pw * 11.9183905733f);   // THETA^-pw
  float interp = extrap * (1.0f / 32.0f);
  float ramp = fminf(fmaxf(((float)dp - 8.0f) * 0.1f, 0.0f), 1.0f);
  return interp * ramp + extrap * (1.0f - ramp);
}

__device__ __forceinline__ void gload_lds16(const void* g, void* l) {
  __builtin_amdgcn_global_load_lds((const __attribute__((address_space(1))) char*)g,
                                   (__attribute__((address_space(3))) char*)l, 16, 0, 0);
}

// ---------------- fused RMSNorm (blocks 0..2047) + w_qkv->bf16 pad (blocks 2048..3071) ----------------
__global__ __launch_bounds__(256) void pre_kernel(const float* __restrict__ x,
                                                  const float* __restrict__ w,
                                                  unsigned short* __restrict__ t_bf,
                                                  const float* __restrict__ wq_src,
                                                  unsigned short* __restrict__ wq_dst) {
  __shared__ float red[256];
  if (blockIdx.x < 2048) {
    int row = blockIdx.x;
    const float4* xr4 = (const float4*)(x + (size_t)row * HID_D);
    const float4* w4 = (const float4*)w;
    float ss = 0.f;
    for (int i = threadIdx.x; i < 720; i += 256) {
      float4 v = xr4[i];
      ss += v.x * v.x + v.y * v.y + v.z * v.z + v.w * v.w;
    }
    red[threadIdx.x] = ss;
    __syncthreads();
    for (int s = 128; s > 0; s >>= 1) {
      if (threadIdx.x < s) red[threadIdx.x] += red[threadIdx.x + s];
      __syncthreads();
    }
    float rs = rsqrtf(red[0] / (float)HID_D + 1e-5f);
    u16x4* ob = (u16x4*)(t_bf + (size_t)row * KPAD);
    for (int i = threadIdx.x; i < 736; i += 256) {
      u16x4 o = {0, 0, 0, 0};
      if (i < 720) {
        float4 v = xr4[i];
        float4 g = w4[i];
        o = { f2bf(v.x * rs * g.x), f2bf(v.y * rs * g.y),
              f2bf(v.z * rs * g.z), f2bf(v.w * rs * g.w) };
      }
      ob[i] = o;
    }
  } else {
    const int total = QKV_N * 736;
    for (int i = (blockIdx.x - 2048) * 256 + threadIdx.x; i < total; i += 1024 * 256) {
      int c4 = i % 736, row = i / 736;
      u16x4 o = {0, 0, 0, 0};
      if (c4 < 720) {
        float4 v = ((const float4*)wq_src)[(size_t)row * 720 + c4];
        o = { f2bf(v.x), f2bf(v.y), f2bf(v.z), f2bf(v.w) };
      }
      ((u16x4*)wq_dst)[i] = o;
    }
  }
}

// ============ 8-phase 256x256 GEMM body ============
// MODE 3: QKV — epilogue applies bias + YaRN RoPE and writes qb/kb/vt directly
//         (each wave's 64 cols = exactly one head; rotation partners are acc[fi][j]/acc[fi][j+2]).
// MODE 1: split-K fp32; kslice0 -> out(+bias+resid), kslice1 -> part (raw).
// Full 3-bit T2 swizzle (source-preswizzled + swizzled ds_read). Counted vmcnt(4).
template <bool NCHECK, int MODE>
__device__ __forceinline__ void gemm_body(const unsigned short* __restrict__ A,
                                          const unsigned short* __restrict__ B,
                                          void* __restrict__ C0,
                                          float* __restrict__ Cpart,
                                          const float* __restrict__ bias,
                                          const float* __restrict__ resid,
                                          unsigned short* __restrict__ qbp,
                                          unsigned short* __restrict__ kbp,
                                          unsigned short* __restrict__ vtp,
                                          const int* __restrict__ positions,
                                          int M, int N, int ld, int nt,
                                          int nbx, int nbxy, int nstore, int swz,
                                          unsigned short* sA, unsigned short* sB) {
  const int tid = threadIdx.x;
  const int lane = tid & 63, wid = tid >> 6;
  const int wr = wid >> 2, wc = wid & 3;
  const int lq = lane & 15, ro = lane >> 4;

  const int kslice = swz / nbxy;
  const int rem = swz - kslice * nbxy;
  const int bx = rem % nbx, by = rem / nbx;
  const int m0 = by * 256, n0 = bx * 256;

  const unsigned short* Ab = A + (size_t)kslice * nt * 64;
  const unsigned short* Bb = B + (size_t)kslice * nt * 64;

  const int R0 = tid >> 3;
  const int g0 = (((tid & 7) ^ (R0 & 7)) << 3);
  const size_t aOff = (size_t)(m0 + R0) * ld + g0;
  size_t bOff[2][2];
#pragma unroll
  for (int h = 0; h < 2; ++h)
#pragma unroll
    for (int r = 0; r < 2; ++r) {
      int rr = n0 + h * 128 + r * 64 + R0;
      if (NCHECK) rr = min(rr, N - 1);
      bOff[h][r] = (size_t)rr * ld + g0;
    }

  const int ck0 = ((ro ^ (lq & 7)) << 3);
  const int ck1 = (((4 + ro) ^ (lq & 7)) << 3);

#define STG_A(BUF, H, KT)                                                        \
  { unsigned short* _d = sA + ((BUF) * 2 + (H)) * 8192 + wid * 512;              \
    const unsigned short* _s = Ab + aOff + (size_t)((H) * 128) * ld + (KT) * 64; \
    gload_lds16(_s, _d); gload_lds16(_s + (size_t)64 * ld, _d + 4096); }
#define STG_B(BUF, H, KT)                                                        \
  { unsigned short* _d = sB + ((BUF) * 2 + (H)) * 8192 + wid * 512;              \
    gload_lds16(Bb + bOff[H][0] + (KT) * 64, _d);                                \
    gload_lds16(Bb + bOff[H][1] + (KT) * 64, _d + 4096); }

  bf16x8 aR[8];
  bf16x8 bR0[4], bR1[4];
  f32x4 acc[8][4] = {};

#define LDA(BUF, S)                                                                        \
  { _Pragma("unroll") for (int ii = 0; ii < 4; ++ii) {                                     \
      const int _r = ((BUF) * 2 + wr) * 8192 + ((S) * 64 + ii * 16 + lq) * 64;             \
      aR[ii * 2 + 0] = *(const bf16x8*)&sA[_r + ck0];                                      \
      aR[ii * 2 + 1] = *(const bf16x8*)&sA[_r + ck1]; } }
#define LDB(BUF, NHF, DST)                                                                 \
  { _Pragma("unroll") for (int jj = 0; jj < 2; ++jj) {                                     \
      const int _r = ((BUF) * 2 + (wc >> 1)) * 8192 +                                      \
                     ((wc & 1) * 64 + ((NHF) * 2 + jj) * 16 + lq) * 64;                    \
      DST[jj * 2 + 0] = *(const bf16x8*)&sB[_r + ck0];                                     \
      DST[jj * 2 + 1] = *(const bf16x8*)&sB[_r + ck1]; } }
#define MFMA16(S, NHF, BREG)                                                               \
  { _Pragma("unroll") for (int ii = 0; ii < 4; ++ii)                                       \
    _Pragma("unroll") for (int jj = 0; jj < 2; ++jj)                                       \
    _Pragma("unroll") for (int kk = 0; kk < 2; ++kk)                                       \
      acc[(S) * 4 + ii][(NHF) * 2 + jj] = __builtin_amdgcn_mfma_f32_16x16x32_bf16(         \
          aR[ii * 2 + kk], BREG[jj * 2 + kk], acc[(S) * 4 + ii][(NHF) * 2 + jj], 0, 0, 0); }
#define PH_MID()                                         \
  __builtin_amdgcn_s_barrier();                          \
  asm volatile("s_waitcnt lgkmcnt(0)" ::: "memory");     \
  __builtin_amdgcn_sched_barrier(0);                     \
  __builtin_amdgcn_s_setprio(1)
#define PH_END()                                         \
  __builtin_amdgcn_s_setprio(0);                         \
  __builtin_amdgcn_s_barrier()

  STG_A(0, 0, 0); STG_A(0, 1, 0); STG_B(0, 0, 0); STG_B(0, 1, 0);
  STG_B(1, 0, 1); STG_B(1, 1, 1);
  asm volatile("s_waitcnt vmcnt(4)" ::: "memory");
  __builtin_amdgcn_s_barrier();

  const int niter = nt >> 1;
  for (int it = 0; it < niter; ++it) {
    const int t = it * 2;
    const bool more = (it + 1 < niter);
    LDA(0, 0); LDB(0, 0, bR0); STG_A(1, 0, t + 1);
    PH_MID(); MFMA16(0, 0, bR0); PH_END();
    LDB(0, 1, bR1); STG_A(1, 1, t + 1);
    PH_MID(); MFMA16(0, 1, bR1); PH_END();
    LDA(0, 1); if (more) STG_B(0, 0, t + 2);
    PH_MID(); MFMA16(1, 1, bR1); PH_END();
    if (more) STG_B(0, 1, t + 2);
    PH_MID(); MFMA16(1, 0, bR0);
    __builtin_amdgcn_s_setprio(0);
    if (more) asm volatile("s_waitcnt vmcnt(4)" ::: "memory");
    else      asm volatile("s_waitcnt vmcnt(0)" ::: "memory");
    __builtin_amdgcn_s_barrier();
    LDA(1, 0); LDB(1, 0, bR0); if (more) STG_A(0, 0, t + 2);
    PH_MID(); MFMA16(0, 0, bR0); PH_END();
    LDB(1, 1, bR1); if (more) STG_A(0, 1, t + 2);
    PH_MID(); MFMA16(0, 1, bR1); PH_END();
    LDA(1, 1); if (more) STG_B(1, 0, t + 3);
    PH_MID(); MFMA16(1, 1, bR1); PH_END();
    if (more) STG_B(1, 1, t + 3);
    PH_MID(); MFMA16(1, 0, bR0);
    __builtin_amdgcn_s_setprio(0);
    if (more) asm volatile("s_waitcnt vmcnt(4)" ::: "memory");
    else      asm volatile("s_waitcnt vmcnt(0)" ::: "memory");
    __builtin_amdgcn_s_barrier();
  }
#undef STG_A
#undef STG_B
#undef LDA
#undef LDB
#undef MFMA16
#undef PH_MID
#undef PH_END

  if (MODE == 3) {
    // this wave's 64 cols = head hh (q: 0..63, k: 64..71, v: 72..79)
    const int cb = n0 + wc * 64;
    const int hh = cb >> 6;
    const float bv0 = bias[cb + lq];
    const float bv1 = bias[cb + 16 + lq];
    const float bv2 = bias[cb + 32 + lq];
    const float bv3 = bias[cb + 48 + lq];
    if (hh < NH + NKV) {
      // RoPE: pairs (acc[*][0],acc[*][2]) -> dims (lq, lq+32); (1,3) -> (16+lq, 48+lq)
      const float invf0 = yarn_invf(lq);
      const float invf1 = yarn_invf(16 + lq);
      unsigned short* dst;
      int stride;
      if (hh < NH) { dst = qbp + hh * HD; stride = ATT_N; }
      else         { dst = kbp + (hh - NH) * HD; stride = NKV * HD; }
#pragma unroll
      for (int fi = 0; fi < 8; ++fi) {
        const int gr = m0 + wr * 128 + fi * 16 + ro * 4;
#pragma unroll
        for (int r = 0; r < 4; ++r) {
          const int t = gr + r;
          const float pos = (float)positions[t];
          float s0, c0, s1, c1;
          sincosf(pos * invf0, &s0, &c0);
          sincosf(pos * invf1, &s1, &c1);
          c0 *= MSCALE; s0 *= MSCALE; c1 *= MSCALE; s1 *= MSCALE;
          const float x1a = acc[fi][0][r] + bv0, x2a = acc[fi][2][r] + bv2;
          const float x1b = acc[fi][1][r] + bv1, x2b = acc[fi][3][r] + bv3;
          unsigned short* p = dst + (size_t)t * stride;
          p[lq]      = f2bf(x1a * c0 - x2a * s0);
          p[lq + 32] = f2bf(x2a * c0 + x1a * s0);
          p[lq + 16] = f2bf(x1b * c1 - x2b * s1);
          p[lq + 48] = f2bf(x2b * c1 + x1b * s1);
        }
      }
    } else {
      // V: vt[(g*64+d)*2048 + t], t = gr..gr+3 contiguous -> ushort4
      const int g = hh - (NH + NKV);
      const float bvs[4] = {bv0, bv1, bv2, bv3};
#pragma unroll
      for (int fi = 0; fi < 8; ++fi) {
        const int gr = m0 + wr * 128 + fi * 16 + ro * 4;
#pragma unroll
        for (int j = 0; j < 4; ++j) {
          const int d = j * 16 + lq;
          ushort4 w = { f2bf(acc[fi][j][0] + bvs[j]), f2bf(acc[fi][j][1] + bvs[j]),
                        f2bf(acc[fi][j][2] + bvs[j]), f2bf(acc[fi][j][3] + bvs[j]) };
          *(ushort4*)(vtp + (size_t)(g * HD + d) * T_SEQ + gr) = w;
        }
      }
    }
  } else {
#pragma unroll
    for (int fi = 0; fi < 8; ++fi) {
      const int gr = m0 + wr * 128 + fi * 16 + ro * 4;
#pragma unroll
      for (int j = 0; j < 4; ++j) {
        const int gc = n0 + wc * 64 + j * 16 + lq;
        if (!NCHECK || gc < N) {
          if (kslice == 0) {
            float* Cf = (float*)C0;
            const float bv = bias[gc];
#pragma unroll
            for (int r = 0; r < 4; ++r) {
              size_t off = (size_t)(gr + r) * nstore + gc;
              Cf[off] = acc[fi][j][r] + bv + resid[off];
            }
          } else {
#pragma unroll
            for (int r = 0; r < 4; ++r)
              Cpart[(size_t)(gr + r) * nstore + gc] = acc[fi][j][r];
          }
        }
      }
    }
  }
}

// ---------------- QKV GEMM+RoPE (160 blocks) fused with w_o->bf16 conversion (96 blocks) ----------------
__global__ __launch_bounds__(512, 2) void qkv_fused_kernel(const unsigned short* __restrict__ A,
                                                           const unsigned short* __restrict__ B,
                                                           const float* __restrict__ bias,
                                                           unsigned short* __restrict__ qb,
                                                           unsigned short* __restrict__ kb,
                                                           unsigned short* __restrict__ vt,
                                                           const int* __restrict__ positions,
                                                           const float* __restrict__ wo_src,
                                                           unsigned short* __restrict__ wo_dst) {
  __shared__ unsigned short sA[2 * 2 * 128 * 64];
  __shared__ unsigned short sB[2 * 2 * 128 * 64];
  const int c = blockIdx.x & 7, q = blockIdx.x >> 3;
  if (q < 20) {
    // each XCD owns M-row c (by == c): 20 N-tiles share one A-panel in L2
    gemm_body<false, 3>(A, B, nullptr, nullptr, bias, nullptr, qb, kb, vt, positions,
                        T_SEQ, QKV_N, KPAD, 46, 20, 160, QKV_N, c * 20 + q, sA, sB);
  } else {
    const int cid = c * 12 + (q - 20);            // 0..95
    const int total = HID_D * 1024;               // float4 count of w_o
    for (int i = cid * 512 + threadIdx.x; i < total; i += 96 * 512) {
      float4 v = ((const float4*)wo_src)[i];
      u16x4 o = { f2bf(v.x), f2bf(v.y), f2bf(v.z), f2bf(v.w) };
      ((u16x4*)wo_dst)[i] = o;
    }
  }
}

// ---------------- out projection, split-K=2 (192 blocks) ----------------
__global__ __launch_bounds__(512, 2) void outproj_kernel(const unsigned short* __restrict__ att,
                                                         const unsigned short* __restrict__ wo_bf,
                                                         float* __restrict__ out,
                                                         float* __restrict__ part,
                                                         const float* __restrict__ b_o,
                                                         const float* __restrict__ x) {
  __shared__ unsigned short sA[2 * 2 * 128 * 64];
  __shared__ unsigned short sB[2 * 2 * 128 * 64];
  const int swz = (blockIdx.x & 7) * 24 + (blockIdx.x >> 3);
  gemm_body<true, 1>(att, wo_bf, out, part, b_o, x, nullptr, nullptr, nullptr, nullptr,
                     T_SEQ, HID_D, ATT_N, 32, 12, 96, HID_D, swz, sA, sB);
}

// ---------------- split-K reduce: out += part ----------------
__global__ __launch_bounds__(256) void reduce_add_kernel(float* __restrict__ out,
                                                         const float* __restrict__ part) {
  int i = blockIdx.x * 256 + threadIdx.x;
  if (i >= T_SEQ * 720) return;
  float4 o = ((const float4*)out)[i];
  float4 p = ((const float4*)part)[i];
  o.x += p.x; o.y += p.y; o.z += p.z; o.w += p.w;
  ((float4*)out)[i] = o;
}

// ---------------- sliding-window attention with sinks ----------------
__global__ __launch_bounds__(256) void attn_kernel(const unsigned short* __restrict__ qb,
                                                   const unsigned short* __restrict__ kb,
                                                   const unsigned short* __restrict__ vt,
                                                   const float* __restrict__ sinks,
                                                   unsigned short* __restrict__ att) {
  const int lane = threadIdx.x & 63;
  const int wid = threadIdx.x >> 6;
  const int q0 = blockIdx.x * 16;
  const int h = blockIdx.y * 4 + wid;
  const int g = h >> 3;
  const int lq = lane & 15;
  const int ro = lane >> 4;

  bf16x8 bq0, bq1;
  {
    const unsigned short* qp = qb + (size_t)(q0 + lq) * ATT_N + h * HD + ro * 8;
    bq0 = *(const bf16x8*)qp;
    bq1 = *(const bf16x8*)(qp + 32);
  }
  float m_run = sinks[h];
  float l_run = 1.0f;
  f32x4 o0 = {0.f, 0.f, 0.f, 0.f}, o1 = o0, o2 = o0, o3 = o0;
  const int qg = q0 + lq;
  const int jstart = (q0 >= WIN) ? q0 - WIN : 0;

  for (int jt = jstart; jt <= q0; jt += 32) {
    f32x4 st0 = {0.f, 0.f, 0.f, 0.f}, st1 = st0;
    {
      int kr = jt + ((lq >> 2) << 3) + (lq & 3);
      int kr0 = min(kr, T_SEQ - 1);
      int kr1 = min(kr + 4, T_SEQ - 1);
      const unsigned short* kp0 = kb + (size_t)kr0 * (NKV * HD) + g * HD + ro * 8;
      const unsigned short* kp1 = kb + (size_t)kr1 * (NKV * HD) + g * HD + ro * 8;
      bf16x8 ka0a = *(const bf16x8*)kp0;
      bf16x8 ka0b = *(const bf16x8*)(kp0 + 32);
      bf16x8 ka1a = *(const bf16x8*)kp1;
      bf16x8 ka1b = *(const bf16x8*)(kp1 + 32);
      st0 = __builtin_amdgcn_mfma_f32_16x16x32_bf16(ka0a, bq0, st0, 0, 0, 0);
      st0 = __builtin_amdgcn_mfma_f32_16x16x32_bf16(ka0b, bq1, st0, 0, 0, 0);
      st1 = __builtin_amdgcn_mfma_f32_16x16x32_bf16(ka1a, bq0, st1, 0, 0, 0);
      st1 = __builtin_amdgcn_mfma_f32_16x16x32_bf16(ka1b, bq1, st1, 0, 0, 0);
    }
    float p[8];
    float tmax = -3.0e30f;
#pragma unroll
    for (int r = 0; r < 4; ++r) {
      int jg0 = jt + ro * 8 + r;
      int jg1 = jg0 + 4;
      float s0 = (jg0 <= qg && (qg - jg0) < WIN) ? st0[r] * RSCALE : -3.0e30f;
      float s1 = (jg1 <= qg && (qg - jg1) < WIN) ? st1[r] * RSCALE : -3.0e30f;
      p[r] = s0;
      p[r + 4] = s1;
      tmax = fmaxf(tmax, fmaxf(s0, s1));
    }
    tmax = fmaxf(tmax, __shfl_xor(tmax, 16));
    tmax = fmaxf(tmax, __shfl_xor(tmax, 32));
    float m_new = fmaxf(m_run, tmax);
    float rescale = expf(m_run - m_new);
    float psum = 0.f;
    bf16x8 pa;
#pragma unroll
    for (int jj = 0; jj < 8; ++jj) {
      float pe = expf(p[jj] - m_new);
      psum += pe;
      pa[jj] = (short)f2bf(pe);
    }
    psum += __shfl_xor(psum, 16);
    psum += __shfl_xor(psum, 32);
    l_run = l_run * rescale + psum;
    m_run = m_new;
    f32x4 rs4;
#pragma unroll
    for (int r = 0; r < 4; ++r) rs4[r] = __shfl(rescale, ro * 4 + r);
    o0 *= rs4; o1 *= rs4; o2 *= rs4; o3 *= rs4;
    int tb = jt + ro * 8;
    if (tb > T_SEQ - 8) tb = T_SEQ - 8;
    const unsigned short* vp = vt + (size_t)(g * HD + lq) * T_SEQ + tb;
    bf16x8 v0 = *(const bf16x8*)vp;
    bf16x8 v1 = *(const bf16x8*)(vp + 16 * T_SEQ);
    bf16x8 v2 = *(const bf16x8*)(vp + 32 * T_SEQ);
    bf16x8 v3 = *(const bf16x8*)(vp + 48 * T_SEQ);
    o0 = __builtin_amdgcn_mfma_f32_16x16x32_bf16(pa, v0, o0, 0, 0, 0);
    o1 = __builtin_amdgcn_mfma_f32_16x16x32_bf16(pa, v1, o1, 0, 0, 0);
    o2 = __builtin_amdgcn_mfma_f32_16x16x32_bf16(pa, v2, o2, 0, 0, 0);
    o3 = __builtin_amdgcn_mfma_f32_16x16x32_bf16(pa, v3, o3, 0, 0, 0);
  }

#pragma unroll
  for (int r = 0; r < 4; ++r) {
    float lr = __shfl(l_run, ro * 4 + r);
    float inv = 1.0f / lr;
    int qrow = q0 + ro * 4 + r;
    unsigned short* op = att + (size_t)qrow * ATT_N + h * HD + lq;
    op[0] = f2bf(o0[r] * inv);
    op[16] = f2bf(o1[r] * inv);
    op[32] = f2bf(o2[r] * inv);
    op[48] = f2bf(o3[r] * inv);
  }
}

extern "C" void kernel_launch(void* const* d_in, const int* in_sizes, int n_in,
                              void* d_out, int out_size, void* d_ws, size_t ws_size,
                              hipStream_t stream) {
  const float* x = (const float*)d_in[0];
  const int* pos = (const int*)d_in[1];
  const float* norm_w = (const float*)d_in[2];
  const float* w_qkv = (const float*)d_in[3];
  const float* b_qkv = (const float*)d_in[4];
  const float* w_o = (const float*)d_in[5];
  const float* b_o = (const float*)d_in[6];
  const float* sinks = (const float*)d_in[7];
  float* out = (float*)d_out;

  unsigned short* t_bf = (unsigned short*)d_ws;                        // [2048][2944]
  unsigned short* wq_bf = t_bf + (size_t)T_SEQ * KPAD;                 // [5120][2944]
  unsigned short* wo_bf = wq_bf + (size_t)QKV_N * KPAD;                // [2880][4096]
  unsigned short* qb = wo_bf + (size_t)HID_D * ATT_N;                  // [2048][4096]
  unsigned short* kb = qb + (size_t)T_SEQ * ATT_N;                     // [2048][512]
  unsigned short* vt = kb + (size_t)T_SEQ * NKV * HD;                  // [8][64][2048]
  unsigned short* att = vt + (size_t)NKV * HD * T_SEQ;                 // [2048][4096]
  // fp32 split-K partial [2048][2880] reuses dead t_bf/wq_bf region (live only after attn)
  float* part = (float*)d_ws;

  // 1. RMSNorm + w_qkv conversion
  pre_kernel<<<3072, 256, 0, stream>>>(x, norm_w, t_bf, w_qkv, wq_bf);
  // 2. QKV GEMM + RoPE/V-transpose epilogue (160 blocks) + w_o conversion (96 blocks)
  qkv_fused_kernel<<<256, 512, 0, stream>>>(t_bf, wq_bf, b_qkv, qb, kb, vt, pos, w_o, wo_bf);
  // 3. attention
  attn_kernel<<<dim3(T_SEQ / 16, NH / 4), 256, 0, stream>>>(qb, kb, vt, sinks, att);
  // 4. out projection split-K=2
  outproj_kernel<<<192, 512, 0, stream>>>(att, wo_bf, out, part, b_o, x);
  // 5. out += part
  reduce_add_kernel<<<(T_SEQ * 720 + 255) / 256, 256, 0, stream>>>(out, part);
}

// Round 8
// 255.492 us; speedup vs baseline: 1.0843x; 1.0843x over previous
//
#include <hip/hip_runtime.h>
#include <hip/hip_bf16.h>
#include <stdint.h>

typedef __attribute__((ext_vector_type(8))) short bf16x8;
typedef __attribute__((ext_vector_type(4))) float f32x4;
typedef __attribute__((ext_vector_type(4))) unsigned short u16x4;

#define T_SEQ 2048
#define HID_D 2880
#define KPAD 2944              // 2880 padded to 46*64
#define NH 64
#define NKV 8
#define HD 64
#define QKV_N 5120
#define ATT_N 4096
#define WIN 128
#define RSCALE 0.125f
#define MSCALE 1.3465735903f
#define ROPE_TOT (T_SEQ * (NH + NKV) * 32)   // 4718592
#define VT_TOT (NKV * HD * T_SEQ)            // 1048576

__device__ __forceinline__ unsigned short f2bf(float f) {
  union { float f; unsigned u; } v; v.f = f;
  unsigned r = v.u + 0x7fffu + ((v.u >> 16) & 1u);
  return (unsigned short)(r >> 16);
}
__device__ __forceinline__ float bf2f(unsigned short u) {
  union { unsigned u; float f; } v; v.u = ((unsigned)u) << 16;
  return v.f;
}

__device__ __forceinline__ void gload_lds16(const void* g, void* l) {
  __builtin_amdgcn_global_load_lds((const __attribute__((address_space(1))) char*)g,
                                   (__attribute__((address_space(3))) char*)l, 16, 0, 0);
}

// ---------------- fused RMSNorm (blocks 0..2047) + w_qkv->bf16 pad (blocks 2048..3071) ----------------
__global__ __launch_bounds__(256) void pre_kernel(const float* __restrict__ x,
                                                  const float* __restrict__ w,
                                                  unsigned short* __restrict__ t_bf,
                                                  const float* __restrict__ wq_src,
                                                  unsigned short* __restrict__ wq_dst) {
  __shared__ float red[256];
  if (blockIdx.x < 2048) {
    int row = blockIdx.x;
    const float4* xr4 = (const float4*)(x + (size_t)row * HID_D);
    const float4* w4 = (const float4*)w;
    float ss = 0.f;
    for (int i = threadIdx.x; i < 720; i += 256) {
      float4 v = xr4[i];
      ss += v.x * v.x + v.y * v.y + v.z * v.z + v.w * v.w;
    }
    red[threadIdx.x] = ss;
    __syncthreads();
    for (int s = 128; s > 0; s >>= 1) {
      if (threadIdx.x < s) red[threadIdx.x] += red[threadIdx.x + s];
      __syncthreads();
    }
    float rs = rsqrtf(red[0] / (float)HID_D + 1e-5f);
    u16x4* ob = (u16x4*)(t_bf + (size_t)row * KPAD);
    for (int i = threadIdx.x; i < 736; i += 256) {
      u16x4 o = {0, 0, 0, 0};
      if (i < 720) {
        float4 v = xr4[i];
        float4 g = w4[i];
        o = { f2bf(v.x * rs * g.x), f2bf(v.y * rs * g.y),
              f2bf(v.z * rs * g.z), f2bf(v.w * rs * g.w) };
      }
      ob[i] = o;
    }
  } else {
    const int total = QKV_N * 736;
    for (int i = (blockIdx.x - 2048) * 256 + threadIdx.x; i < total; i += 1024 * 256) {
      int c4 = i % 736, row = i / 736;
      u16x4 o = {0, 0, 0, 0};
      if (c4 < 720) {
        float4 v = ((const float4*)wq_src)[(size_t)row * 720 + c4];
        o = { f2bf(v.x), f2bf(v.y), f2bf(v.z), f2bf(v.w) };
      }
      ((u16x4*)wq_dst)[i] = o;
    }
  }
}

// ============ 8-phase 256x256 GEMM body (shared by QKV and out-proj) ============
// MODE 2: single-K, bf16 output + bias.  MODE 1: split-K, atomicAdd fp32 into C0
// (C0 pre-initialized to x + b_o by the qkv_fused spare blocks).
// Full 3-bit T2 swizzle (source-preswizzled + swizzled ds_read). Counted vmcnt(4).
template <bool NCHECK, int MODE>
__device__ __forceinline__ void gemm_body(const unsigned short* __restrict__ A,
                                          const unsigned short* __restrict__ B,
                                          void* __restrict__ C0,
                                          const float* __restrict__ bias,
                                          int M, int N, int ld, int nt,
                                          int nbx, int nbxy, int nstore, int swz,
                                          unsigned short* sA, unsigned short* sB) {
  const int tid = threadIdx.x;
  const int lane = tid & 63, wid = tid >> 6;
  const int wr = wid >> 2, wc = wid & 3;
  const int lq = lane & 15, ro = lane >> 4;

  const int kslice = swz / nbxy;
  const int rem = swz - kslice * nbxy;
  const int bx = rem % nbx, by = rem / nbx;
  const int m0 = by * 256, n0 = bx * 256;

  const unsigned short* Ab = A + (size_t)kslice * nt * 64;
  const unsigned short* Bb = B + (size_t)kslice * nt * 64;

  const int R0 = tid >> 3;
  const int g0 = (((tid & 7) ^ (R0 & 7)) << 3);
  const size_t aOff = (size_t)(m0 + R0) * ld + g0;
  size_t bOff[2][2];
#pragma unroll
  for (int h = 0; h < 2; ++h)
#pragma unroll
    for (int r = 0; r < 2; ++r) {
      int rr = n0 + h * 128 + r * 64 + R0;
      if (NCHECK) rr = min(rr, N - 1);
      bOff[h][r] = (size_t)rr * ld + g0;
    }

  const int ck0 = ((ro ^ (lq & 7)) << 3);
  const int ck1 = (((4 + ro) ^ (lq & 7)) << 3);

#define STG_A(BUF, H, KT)                                                        \
  { unsigned short* _d = sA + ((BUF) * 2 + (H)) * 8192 + wid * 512;              \
    const unsigned short* _s = Ab + aOff + (size_t)((H) * 128) * ld + (KT) * 64; \
    gload_lds16(_s, _d); gload_lds16(_s + (size_t)64 * ld, _d + 4096); }
#define STG_B(BUF, H, KT)                                                        \
  { unsigned short* _d = sB + ((BUF) * 2 + (H)) * 8192 + wid * 512;              \
    gload_lds16(Bb + bOff[H][0] + (KT) * 64, _d);                                \
    gload_lds16(Bb + bOff[H][1] + (KT) * 64, _d + 4096); }

  bf16x8 aR[8];
  bf16x8 bR0[4], bR1[4];
  f32x4 acc[8][4] = {};

#define LDA(BUF, S)                                                                        \
  { _Pragma("unroll") for (int ii = 0; ii < 4; ++ii) {                                     \
      const int _r = ((BUF) * 2 + wr) * 8192 + ((S) * 64 + ii * 16 + lq) * 64;             \
      aR[ii * 2 + 0] = *(const bf16x8*)&sA[_r + ck0];                                      \
      aR[ii * 2 + 1] = *(const bf16x8*)&sA[_r + ck1]; } }
#define LDB(BUF, NHF, DST)                                                                 \
  { _Pragma("unroll") for (int jj = 0; jj < 2; ++jj) {                                     \
      const int _r = ((BUF) * 2 + (wc >> 1)) * 8192 +                                      \
                     ((wc & 1) * 64 + ((NHF) * 2 + jj) * 16 + lq) * 64;                    \
      DST[jj * 2 + 0] = *(const bf16x8*)&sB[_r + ck0];                                     \
      DST[jj * 2 + 1] = *(const bf16x8*)&sB[_r + ck1]; } }
#define MFMA16(S, NHF, BREG)                                                               \
  { _Pragma("unroll") for (int ii = 0; ii < 4; ++ii)                                       \
    _Pragma("unroll") for (int jj = 0; jj < 2; ++jj)                                       \
    _Pragma("unroll") for (int kk = 0; kk < 2; ++kk)                                       \
      acc[(S) * 4 + ii][(NHF) * 2 + jj] = __builtin_amdgcn_mfma_f32_16x16x32_bf16(         \
          aR[ii * 2 + kk], BREG[jj * 2 + kk], acc[(S) * 4 + ii][(NHF) * 2 + jj], 0, 0, 0); }
#define PH_MID()                                         \
  __builtin_amdgcn_s_barrier();                          \
  asm volatile("s_waitcnt lgkmcnt(0)" ::: "memory");     \
  __builtin_amdgcn_sched_barrier(0);                     \
  __builtin_amdgcn_s_setprio(1)
#define PH_END()                                         \
  __builtin_amdgcn_s_setprio(0);                         \
  __builtin_amdgcn_s_barrier()

  STG_A(0, 0, 0); STG_A(0, 1, 0); STG_B(0, 0, 0); STG_B(0, 1, 0);
  STG_B(1, 0, 1); STG_B(1, 1, 1);
  asm volatile("s_waitcnt vmcnt(4)" ::: "memory");
  __builtin_amdgcn_s_barrier();

  const int niter = nt >> 1;
  for (int it = 0; it < niter; ++it) {
    const int t = it * 2;
    const bool more = (it + 1 < niter);
    LDA(0, 0); LDB(0, 0, bR0); STG_A(1, 0, t + 1);
    PH_MID(); MFMA16(0, 0, bR0); PH_END();
    LDB(0, 1, bR1); STG_A(1, 1, t + 1);
    PH_MID(); MFMA16(0, 1, bR1); PH_END();
    LDA(0, 1); if (more) STG_B(0, 0, t + 2);
    PH_MID(); MFMA16(1, 1, bR1); PH_END();
    if (more) STG_B(0, 1, t + 2);
    PH_MID(); MFMA16(1, 0, bR0);
    __builtin_amdgcn_s_setprio(0);
    if (more) asm volatile("s_waitcnt vmcnt(4)" ::: "memory");
    else      asm volatile("s_waitcnt vmcnt(0)" ::: "memory");
    __builtin_amdgcn_s_barrier();
    LDA(1, 0); LDB(1, 0, bR0); if (more) STG_A(0, 0, t + 2);
    PH_MID(); MFMA16(0, 0, bR0); PH_END();
    LDB(1, 1, bR1); if (more) STG_A(0, 1, t + 2);
    PH_MID(); MFMA16(0, 1, bR1); PH_END();
    LDA(1, 1); if (more) STG_B(1, 0, t + 3);
    PH_MID(); MFMA16(1, 1, bR1); PH_END();
    if (more) STG_B(1, 1, t + 3);
    PH_MID(); MFMA16(1, 0, bR0);
    __builtin_amdgcn_s_setprio(0);
    if (more) asm volatile("s_waitcnt vmcnt(4)" ::: "memory");
    else      asm volatile("s_waitcnt vmcnt(0)" ::: "memory");
    __builtin_amdgcn_s_barrier();
  }
#undef STG_A
#undef STG_B
#undef LDA
#undef LDB
#undef MFMA16
#undef PH_MID
#undef PH_END

#pragma unroll
  for (int fi = 0; fi < 8; ++fi) {
    const int gr = m0 + wr * 128 + fi * 16 + ro * 4;
#pragma unroll
    for (int j = 0; j < 4; ++j) {
      const int gc = n0 + wc * 64 + j * 16 + lq;
      if (!NCHECK || gc < N) {
        if (MODE == 2) {
          const float bv = bias[gc];
          unsigned short* Cs = (unsigned short*)C0;
#pragma unroll
          for (int r = 0; r < 4; ++r)
            Cs[(size_t)(gr + r) * nstore + gc] = f2bf(acc[fi][j][r] + bv);
        } else {
          // split-K: out pre-initialized to x + b_o; both slices accumulate
          float* Cf = (float*)C0;
#pragma unroll
          for (int r = 0; r < 4; ++r)
            atomicAdd(&Cf[(size_t)(gr + r) * nstore + gc], acc[fi][j][r]);
        }
      }
    }
  }
}

// ---------------- QKV GEMM (160 blocks) + spare blocks: w_o->bf16 conversion AND out=x+b_o init ----------------
__global__ __launch_bounds__(512, 2) void qkv_fused_kernel(const unsigned short* __restrict__ A,
                                                           const unsigned short* __restrict__ B,
                                                           unsigned short* __restrict__ C,
                                                           const float* __restrict__ bias,
                                                           const float* __restrict__ wo_src,
                                                           unsigned short* __restrict__ wo_dst,
                                                           const float* __restrict__ x,
                                                           const float* __restrict__ b_o,
                                                           float* __restrict__ out) {
  __shared__ unsigned short sA[2 * 2 * 128 * 64];
  __shared__ unsigned short sB[2 * 2 * 128 * 64];
  const int c = blockIdx.x & 7, q = blockIdx.x >> 3;
  if (q < 20) {
    // each XCD owns M-row c (by == c): 20 N-tiles share one A-panel in L2
    gemm_body<false, 2>(A, B, C, bias,
                        T_SEQ, QKV_N, KPAD, 46, 20, 160, QKV_N, c * 20 + q, sA, sB);
  } else {
    const int cid = c * 12 + (q - 20);            // 0..95
    // (a) w_o -> bf16
    const int total = HID_D * 1024;               // float4 count of w_o
    for (int i = cid * 512 + threadIdx.x; i < total; i += 96 * 512) {
      float4 v = ((const float4*)wo_src)[i];
      u16x4 o = { f2bf(v.x), f2bf(v.y), f2bf(v.z), f2bf(v.w) };
      ((u16x4*)wo_dst)[i] = o;
    }
    // (b) out = x + b_o (pre-init for the split-K atomic out-proj)
    const int tot2 = T_SEQ * 720;                 // float4 count of out
    for (int i = cid * 512 + threadIdx.x; i < tot2; i += 96 * 512) {
      int c4 = i % 720;
      float4 xv = ((const float4*)x)[i];
      float4 bv = ((const float4*)b_o)[c4];
      float4 o = { xv.x + bv.x, xv.y + bv.y, xv.z + bv.z, xv.w + bv.w };
      ((float4*)out)[i] = o;
    }
  }
}

// ---------------- out projection, split-K=2 (192 blocks), atomic accumulate into out ----------------
__global__ __launch_bounds__(512, 2) void outproj_kernel(const unsigned short* __restrict__ att,
                                                         const unsigned short* __restrict__ wo_bf,
                                                         float* __restrict__ out) {
  __shared__ unsigned short sA[2 * 2 * 128 * 64];
  __shared__ unsigned short sB[2 * 2 * 128 * 64];
  const int swz = (blockIdx.x & 7) * 24 + (blockIdx.x >> 3);
  gemm_body<true, 1>(att, wo_bf, out, nullptr,
                     T_SEQ, HID_D, ATT_N, 32, 12, 96, HID_D, swz, sA, sB);
}

// ---------------- fused YaRN RoPE (q,k) + V transpose, reading bf16 qkv ----------------
__global__ __launch_bounds__(256) void ropev_kernel(const unsigned short* __restrict__ qkvb,
                                                    const int* __restrict__ positions,
                                                    unsigned short* __restrict__ qb,
                                                    unsigned short* __restrict__ kb,
                                                    unsigned short* __restrict__ vt) {
  int idx = blockIdx.x * 256 + threadIdx.x;
  if (idx < ROPE_TOT) {
    int d = idx & 31;
    int head = (idx >> 5) % (NH + NKV);
    int t = idx / ((NH + NKV) * 32);
    float pw = (float)d * (1.0f / 32.0f);
    float extrap = expf(-pw * 11.9183905733f);
    float interp = extrap * (1.0f / 32.0f);
    float ramp = fminf(fmaxf(((float)d - 8.0f) * 0.1f, 0.0f), 1.0f);
    float invf = interp * ramp + extrap * (1.0f - ramp);
    float fr = (float)positions[t] * invf;
    float s, c;
    sincosf(fr, &s, &c);
    c *= MSCALE;
    s *= MSCALE;
    if (head < NH) {
      const unsigned short* b = qkvb + (size_t)t * QKV_N + head * HD + d;
      float x1 = bf2f(b[0]), x2 = bf2f(b[32]);
      unsigned short* ob = qb + (size_t)t * ATT_N + head * HD + d;
      ob[0] = f2bf(x1 * c - x2 * s);
      ob[32] = f2bf(x2 * c + x1 * s);
    } else {
      int gk = head - NH;
      const unsigned short* b = qkvb + (size_t)t * QKV_N + NH * HD + gk * HD + d;
      float x1 = bf2f(b[0]), x2 = bf2f(b[32]);
      unsigned short* ob = kb + (size_t)t * (NKV * HD) + gk * HD + d;
      ob[0] = f2bf(x1 * c - x2 * s);
      ob[32] = f2bf(x2 * c + x1 * s);
    }
  } else {
    int i2 = idx - ROPE_TOT;                      // (g*64+d)*2048 + t
    int t = i2 & (T_SEQ - 1);
    int d = (i2 >> 11) & 63;
    int g = i2 >> 17;
    vt[i2] = qkvb[(size_t)t * QKV_N + (NH + NKV) * HD + g * HD + d];
  }
}

// ---------------- sliding-window attention with sinks ----------------
__global__ __launch_bounds__(256) void attn_kernel(const unsigned short* __restrict__ qb,
                                                   const unsigned short* __restrict__ kb,
                                                   const unsigned short* __restrict__ vt,
                                                   const float* __restrict__ sinks,
                                                   unsigned short* __restrict__ att) {
  const int lane = threadIdx.x & 63;
  const int wid = threadIdx.x >> 6;
  const int q0 = blockIdx.x * 16;
  const int h = blockIdx.y * 4 + wid;
  const int g = h >> 3;
  const int lq = lane & 15;
  const int ro = lane >> 4;

  bf16x8 bq0, bq1;
  {
    const unsigned short* qp = qb + (size_t)(q0 + lq) * ATT_N + h * HD + ro * 8;
    bq0 = *(const bf16x8*)qp;
    bq1 = *(const bf16x8*)(qp + 32);
  }
  float m_run = sinks[h];
  float l_run = 1.0f;
  f32x4 o0 = {0.f, 0.f, 0.f, 0.f}, o1 = o0, o2 = o0, o3 = o0;
  const int qg = q0 + lq;
  const int jstart = (q0 >= WIN) ? q0 - WIN : 0;

  for (int jt = jstart; jt <= q0; jt += 32) {
    f32x4 st0 = {0.f, 0.f, 0.f, 0.f}, st1 = st0;
    {
      int kr = jt + ((lq >> 2) << 3) + (lq & 3);
      int kr0 = min(kr, T_SEQ - 1);
      int kr1 = min(kr + 4, T_SEQ - 1);
      const unsigned short* kp0 = kb + (size_t)kr0 * (NKV * HD) + g * HD + ro * 8;
      const unsigned short* kp1 = kb + (size_t)kr1 * (NKV * HD) + g * HD + ro * 8;
      bf16x8 ka0a = *(const bf16x8*)kp0;
      bf16x8 ka0b = *(const bf16x8*)(kp0 + 32);
      bf16x8 ka1a = *(const bf16x8*)kp1;
      bf16x8 ka1b = *(const bf16x8*)(kp1 + 32);
      st0 = __builtin_amdgcn_mfma_f32_16x16x32_bf16(ka0a, bq0, st0, 0, 0, 0);
      st0 = __builtin_amdgcn_mfma_f32_16x16x32_bf16(ka0b, bq1, st0, 0, 0, 0);
      st1 = __builtin_amdgcn_mfma_f32_16x16x32_bf16(ka1a, bq0, st1, 0, 0, 0);
      st1 = __builtin_amdgcn_mfma_f32_16x16x32_bf16(ka1b, bq1, st1, 0, 0, 0);
    }
    float p[8];
    float tmax = -3.0e30f;
#pragma unroll
    for (int r = 0; r < 4; ++r) {
      int jg0 = jt + ro * 8 + r;
      int jg1 = jg0 + 4;
      float s0 = (jg0 <= qg && (qg - jg0) < WIN) ? st0[r] * RSCALE : -3.0e30f;
      float s1 = (jg1 <= qg && (qg - jg1) < WIN) ? st1[r] * RSCALE : -3.0e30f;
      p[r] = s0;
      p[r + 4] = s1;
      tmax = fmaxf(tmax, fmaxf(s0, s1));
    }
    tmax = fmaxf(tmax, __shfl_xor(tmax, 16));
    tmax = fmaxf(tmax, __shfl_xor(tmax, 32));
    float m_new = fmaxf(m_run, tmax);
    float rescale = expf(m_run - m_new);
    float psum = 0.f;
    bf16x8 pa;
#pragma unroll
    for (int jj = 0; jj < 8; ++jj) {
      float pe = expf(p[jj] - m_new);
      psum += pe;
      pa[jj] = (short)f2bf(pe);
    }
    psum += __shfl_xor(psum, 16);
    psum += __shfl_xor(psum, 32);
    l_run = l_run * rescale + psum;
    m_run = m_new;
    f32x4 rs4;
#pragma unroll
    for (int r = 0; r < 4; ++r) rs4[r] = __shfl(rescale, ro * 4 + r);
    o0 *= rs4; o1 *= rs4; o2 *= rs4; o3 *= rs4;
    int tb = jt + ro * 8;
    if (tb > T_SEQ - 8) tb = T_SEQ - 8;
    const unsigned short* vp = vt + (size_t)(g * HD + lq) * T_SEQ + tb;
    bf16x8 v0 = *(const bf16x8*)vp;
    bf16x8 v1 = *(const bf16x8*)(vp + 16 * T_SEQ);
    bf16x8 v2 = *(const bf16x8*)(vp + 32 * T_SEQ);
    bf16x8 v3 = *(const bf16x8*)(vp + 48 * T_SEQ);
    o0 = __builtin_amdgcn_mfma_f32_16x16x32_bf16(pa, v0, o0, 0, 0, 0);
    o1 = __builtin_amdgcn_mfma_f32_16x16x32_bf16(pa, v1, o1, 0, 0, 0);
    o2 = __builtin_amdgcn_mfma_f32_16x16x32_bf16(pa, v2, o2, 0, 0, 0);
    o3 = __builtin_amdgcn_mfma_f32_16x16x32_bf16(pa, v3, o3, 0, 0, 0);
  }

#pragma unroll
  for (int r = 0; r < 4; ++r) {
    float lr = __shfl(l_run, ro * 4 + r);
    float inv = 1.0f / lr;
    int qrow = q0 + ro * 4 + r;
    unsigned short* op = att + (size_t)qrow * ATT_N + h * HD + lq;
    op[0] = f2bf(o0[r] * inv);
    op[16] = f2bf(o1[r] * inv);
    op[32] = f2bf(o2[r] * inv);
    op[48] = f2bf(o3[r] * inv);
  }
}

extern "C" void kernel_launch(void* const* d_in, const int* in_sizes, int n_in,
                              void* d_out, int out_size, void* d_ws, size_t ws_size,
                              hipStream_t stream) {
  const float* x = (const float*)d_in[0];
  const int* pos = (const int*)d_in[1];
  const float* norm_w = (const float*)d_in[2];
  const float* w_qkv = (const float*)d_in[3];
  const float* b_qkv = (const float*)d_in[4];
  const float* w_o = (const float*)d_in[5];
  const float* b_o = (const float*)d_in[6];
  const float* sinks = (const float*)d_in[7];
  float* out = (float*)d_out;

  unsigned short* t_bf = (unsigned short*)d_ws;                        // [2048][2944]
  unsigned short* wq_bf = t_bf + (size_t)T_SEQ * KPAD;                 // [5120][2944]
  unsigned short* wo_bf = wq_bf + (size_t)QKV_N * KPAD;                // [2880][4096]
  unsigned short* qkv_bf = wo_bf + (size_t)HID_D * ATT_N;              // [2048][5120] bf16
  unsigned short* qb = qkv_bf + (size_t)T_SEQ * QKV_N;                 // [2048][4096]
  unsigned short* kb = qb + (size_t)T_SEQ * ATT_N;                     // [2048][512]
  unsigned short* vt = kb + (size_t)T_SEQ * NKV * HD;                  // [8][64][2048]
  unsigned short* att = vt + (size_t)NKV * HD * T_SEQ;                 // [2048][4096]

  // 1. RMSNorm + w_qkv conversion
  pre_kernel<<<3072, 256, 0, stream>>>(x, norm_w, t_bf, w_qkv, wq_bf);
  // 2. QKV GEMM (160 blocks) + spare 96 blocks: w_o conversion + out=x+b_o init
  qkv_fused_kernel<<<256, 512, 0, stream>>>(t_bf, wq_bf, qkv_bf, b_qkv, w_o, wo_bf,
                                            x, b_o, out);
  // 3. RoPE + V transpose
  ropev_kernel<<<(ROPE_TOT + VT_TOT) / 256, 256, 0, stream>>>(qkv_bf, pos, qb, kb, vt);
  // 4. attention
  attn_kernel<<<dim3(T_SEQ / 16, NH / 4), 256, 0, stream>>>(qb, kb, vt, sinks, att);
  // 5. out projection split-K=2, atomic accumulate into pre-initialized out
  outproj_kernel<<<192, 512, 0, stream>>>(att, wo_bf, out);
}

// Round 9
// 249.938 us; speedup vs baseline: 1.1084x; 1.0222x over previous
//
#include <hip/hip_runtime.h>
#include <hip/hip_bf16.h>
#include <stdint.h>

typedef __attribute__((ext_vector_type(8))) short bf16x8;
typedef __attribute__((ext_vector_type(4))) float f32x4;
typedef __attribute__((ext_vector_type(4))) unsigned short u16x4;

#define T_SEQ 2048
#define HID_D 2880
#define KPAD 2944              // 2880 padded to 46*64
#define NH 64
#define NKV 8
#define HD 64
#define QKV_N 5120
#define ATT_N 4096
#define WIN 128
#define RSCALE 0.125f
#define MSCALE 1.3465735903f
#define ROPE_TOT (T_SEQ * (NH + NKV) * 32)   // 4718592
#define VT_TOT (NKV * HD * T_SEQ)            // 1048576

__device__ __forceinline__ unsigned short f2bf(float f) {
  union { float f; unsigned u; } v; v.f = f;
  unsigned r = v.u + 0x7fffu + ((v.u >> 16) & 1u);
  return (unsigned short)(r >> 16);
}
__device__ __forceinline__ float bf2f(unsigned short u) {
  union { unsigned u; float f; } v; v.u = ((unsigned)u) << 16;
  return v.f;
}

__device__ __forceinline__ void gload_lds16(const void* g, void* l) {
  __builtin_amdgcn_global_load_lds((const __attribute__((address_space(1))) char*)g,
                                   (__attribute__((address_space(3))) char*)l, 16, 0, 0);
}

// ---------------- fused RMSNorm (blocks 0..2047) + w_qkv->bf16 pad (blocks 2048..3071) ----------------
__global__ __launch_bounds__(256) void pre_kernel(const float* __restrict__ x,
                                                  const float* __restrict__ w,
                                                  unsigned short* __restrict__ t_bf,
                                                  const float* __restrict__ wq_src,
                                                  unsigned short* __restrict__ wq_dst) {
  __shared__ float red[256];
  if (blockIdx.x < 2048) {
    int row = blockIdx.x;
    const float4* xr4 = (const float4*)(x + (size_t)row * HID_D);
    const float4* w4 = (const float4*)w;
    float ss = 0.f;
    for (int i = threadIdx.x; i < 720; i += 256) {
      float4 v = xr4[i];
      ss += v.x * v.x + v.y * v.y + v.z * v.z + v.w * v.w;
    }
    red[threadIdx.x] = ss;
    __syncthreads();
    for (int s = 128; s > 0; s >>= 1) {
      if (threadIdx.x < s) red[threadIdx.x] += red[threadIdx.x + s];
      __syncthreads();
    }
    float rs = rsqrtf(red[0] / (float)HID_D + 1e-5f);
    u16x4* ob = (u16x4*)(t_bf + (size_t)row * KPAD);
    for (int i = threadIdx.x; i < 736; i += 256) {
      u16x4 o = {0, 0, 0, 0};
      if (i < 720) {
        float4 v = xr4[i];
        float4 g = w4[i];
        o = { f2bf(v.x * rs * g.x), f2bf(v.y * rs * g.y),
              f2bf(v.z * rs * g.z), f2bf(v.w * rs * g.w) };
      }
      ob[i] = o;
    }
  } else {
    const int total = QKV_N * 736;
    for (int i = (blockIdx.x - 2048) * 256 + threadIdx.x; i < total; i += 1024 * 256) {
      int c4 = i % 736, row = i / 736;
      u16x4 o = {0, 0, 0, 0};
      if (c4 < 720) {
        float4 v = ((const float4*)wq_src)[(size_t)row * 720 + c4];
        o = { f2bf(v.x), f2bf(v.y), f2bf(v.z), f2bf(v.w) };
      }
      ((u16x4*)wq_dst)[i] = o;
    }
  }
}

// ============ 8-phase 256x256 GEMM body (QKV): bf16 output + bias ============
// Full 3-bit T2 swizzle (source-preswizzled + swizzled ds_read). Counted vmcnt(4).
__device__ __forceinline__ void gemm_body(const unsigned short* __restrict__ A,
                                          const unsigned short* __restrict__ B,
                                          unsigned short* __restrict__ C,
                                          const float* __restrict__ bias,
                                          int N, int ld, int nt,
                                          int nbx, int nstore, int swz,
                                          unsigned short* sA, unsigned short* sB) {
  const int tid = threadIdx.x;
  const int lane = tid & 63, wid = tid >> 6;
  const int wr = wid >> 2, wc = wid & 3;
  const int lq = lane & 15, ro = lane >> 4;

  const int bx = swz % nbx, by = swz / nbx;
  const int m0 = by * 256, n0 = bx * 256;

  const int R0 = tid >> 3;
  const int g0 = (((tid & 7) ^ (R0 & 7)) << 3);
  const size_t aOff = (size_t)(m0 + R0) * ld + g0;
  size_t bOff[2][2];
#pragma unroll
  for (int h = 0; h < 2; ++h)
#pragma unroll
    for (int r = 0; r < 2; ++r) {
      int rr = n0 + h * 128 + r * 64 + R0;
      bOff[h][r] = (size_t)rr * ld + g0;
    }

  const int ck0 = ((ro ^ (lq & 7)) << 3);
  const int ck1 = (((4 + ro) ^ (lq & 7)) << 3);

#define STG_A(BUF, H, KT)                                                        \
  { unsigned short* _d = sA + ((BUF) * 2 + (H)) * 8192 + wid * 512;              \
    const unsigned short* _s = A + aOff + (size_t)((H) * 128) * ld + (KT) * 64;  \
    gload_lds16(_s, _d); gload_lds16(_s + (size_t)64 * ld, _d + 4096); }
#define STG_B(BUF, H, KT)                                                        \
  { unsigned short* _d = sB + ((BUF) * 2 + (H)) * 8192 + wid * 512;              \
    gload_lds16(B + bOff[H][0] + (KT) * 64, _d);                                 \
    gload_lds16(B + bOff[H][1] + (KT) * 64, _d + 4096); }

  bf16x8 aR[8];
  bf16x8 bR0[4], bR1[4];
  f32x4 acc[8][4] = {};

#define LDA(BUF, S)                                                                        \
  { _Pragma("unroll") for (int ii = 0; ii < 4; ++ii) {                                     \
      const int _r = ((BUF) * 2 + wr) * 8192 + ((S) * 64 + ii * 16 + lq) * 64;             \
      aR[ii * 2 + 0] = *(const bf16x8*)&sA[_r + ck0];                                      \
      aR[ii * 2 + 1] = *(const bf16x8*)&sA[_r + ck1]; } }
#define LDB(BUF, NHF, DST)                                                                 \
  { _Pragma("unroll") for (int jj = 0; jj < 2; ++jj) {                                     \
      const int _r = ((BUF) * 2 + (wc >> 1)) * 8192 +                                      \
                     ((wc & 1) * 64 + ((NHF) * 2 + jj) * 16 + lq) * 64;                    \
      DST[jj * 2 + 0] = *(const bf16x8*)&sB[_r + ck0];                                     \
      DST[jj * 2 + 1] = *(const bf16x8*)&sB[_r + ck1]; } }
#define MFMA16(S, NHF, BREG)                                                               \
  { _Pragma("unroll") for (int ii = 0; ii < 4; ++ii)                                       \
    _Pragma("unroll") for (int jj = 0; jj < 2; ++jj)                                       \
    _Pragma("unroll") for (int kk = 0; kk < 2; ++kk)                                       \
      acc[(S) * 4 + ii][(NHF) * 2 + jj] = __builtin_amdgcn_mfma_f32_16x16x32_bf16(         \
          aR[ii * 2 + kk], BREG[jj * 2 + kk], acc[(S) * 4 + ii][(NHF) * 2 + jj], 0, 0, 0); }
#define PH_MID()                                         \
  __builtin_amdgcn_s_barrier();                          \
  asm volatile("s_waitcnt lgkmcnt(0)" ::: "memory");     \
  __builtin_amdgcn_sched_barrier(0);                     \
  __builtin_amdgcn_s_setprio(1)
#define PH_END()                                         \
  __builtin_amdgcn_s_setprio(0);                         \
  __builtin_amdgcn_s_barrier()

  STG_A(0, 0, 0); STG_A(0, 1, 0); STG_B(0, 0, 0); STG_B(0, 1, 0);
  STG_B(1, 0, 1); STG_B(1, 1, 1);
  asm volatile("s_waitcnt vmcnt(4)" ::: "memory");
  __builtin_amdgcn_s_barrier();

  const int niter = nt >> 1;
  for (int it = 0; it < niter; ++it) {
    const int t = it * 2;
    const bool more = (it + 1 < niter);
    LDA(0, 0); LDB(0, 0, bR0); STG_A(1, 0, t + 1);
    PH_MID(); MFMA16(0, 0, bR0); PH_END();
    LDB(0, 1, bR1); STG_A(1, 1, t + 1);
    PH_MID(); MFMA16(0, 1, bR1); PH_END();
    LDA(0, 1); if (more) STG_B(0, 0, t + 2);
    PH_MID(); MFMA16(1, 1, bR1); PH_END();
    if (more) STG_B(0, 1, t + 2);
    PH_MID(); MFMA16(1, 0, bR0);
    __builtin_amdgcn_s_setprio(0);
    if (more) asm volatile("s_waitcnt vmcnt(4)" ::: "memory");
    else      asm volatile("s_waitcnt vmcnt(0)" ::: "memory");
    __builtin_amdgcn_s_barrier();
    LDA(1, 0); LDB(1, 0, bR0); if (more) STG_A(0, 0, t + 2);
    PH_MID(); MFMA16(0, 0, bR0); PH_END();
    LDB(1, 1, bR1); if (more) STG_A(0, 1, t + 2);
    PH_MID(); MFMA16(0, 1, bR1); PH_END();
    LDA(1, 1); if (more) STG_B(1, 0, t + 3);
    PH_MID(); MFMA16(1, 1, bR1); PH_END();
    if (more) STG_B(1, 1, t + 3);
    PH_MID(); MFMA16(1, 0, bR0);
    __builtin_amdgcn_s_setprio(0);
    if (more) asm volatile("s_waitcnt vmcnt(4)" ::: "memory");
    else      asm volatile("s_waitcnt vmcnt(0)" ::: "memory");
    __builtin_amdgcn_s_barrier();
  }
#undef STG_A
#undef STG_B
#undef LDA
#undef LDB
#undef MFMA16
#undef PH_MID
#undef PH_END

#pragma unroll
  for (int fi = 0; fi < 8; ++fi) {
    const int gr = m0 + wr * 128 + fi * 16 + ro * 4;
#pragma unroll
    for (int j = 0; j < 4; ++j) {
      const int gc = n0 + wc * 64 + j * 16 + lq;
      const float bv = bias[gc];
#pragma unroll
      for (int r = 0; r < 4; ++r)
        C[(size_t)(gr + r) * nstore + gc] = f2bf(acc[fi][j][r] + bv);
    }
  }
}

// ---------------- QKV GEMM (160 blocks, 4Mx5N per XCD) + w_o->bf16 conversion (96 blocks) ----------------
__global__ __launch_bounds__(512, 2) void qkv_fused_kernel(const unsigned short* __restrict__ A,
                                                           const unsigned short* __restrict__ B,
                                                           unsigned short* __restrict__ C,
                                                           const float* __restrict__ bias,
                                                           const float* __restrict__ wo_src,
                                                           unsigned short* __restrict__ wo_dst) {
  __shared__ unsigned short sA[2 * 2 * 128 * 64];
  __shared__ unsigned short sB[2 * 2 * 128 * 64];
  const int c = blockIdx.x & 7, q = blockIdx.x >> 3;
  if (q < 20) {
    // XCD c owns a 4M x 5N tile rectangle: A 6MB + B 7.5MB per-XCD L2 footprint
    const int by = (c & 1) * 4 + (q & 3);
    const int bx = (c >> 1) * 5 + (q >> 2);
    gemm_body(A, B, C, bias, QKV_N, KPAD, 46, 20, QKV_N, by * 20 + bx, sA, sB);
  } else {
    const int cid = c * 12 + (q - 20);            // 0..95
    const int total = HID_D * 1024;               // float4 count of w_o
    for (int i = cid * 512 + threadIdx.x; i < total; i += 96 * 512) {
      float4 v = ((const float4*)wo_src)[i];
      u16x4 o = { f2bf(v.x), f2bf(v.y), f2bf(v.z), f2bf(v.w) };
      ((u16x4*)wo_dst)[i] = o;
    }
  }
}

// ============ out projection: 128x256 tile, FULL K=4096, 192 blocks ============
// 4-phase/iter (2 K-tiles), A 2-buf (32KB), B 3-buf (96KB), counted vmcnt(6),
// epilogue: out = acc + b_o + x (fp32). No split-K, no atomics, no reduce pass.
__global__ __launch_bounds__(512, 2) void outproj128_kernel(const unsigned short* __restrict__ att,
                                                            const unsigned short* __restrict__ wo,
                                                            float* __restrict__ out,
                                                            const float* __restrict__ b_o,
                                                            const float* __restrict__ x) {
  __shared__ unsigned short sA[2 * 128 * 64];       // 32 KiB
  __shared__ unsigned short sB[3 * 2 * 128 * 64];   // 96 KiB

  const int tid = threadIdx.x;
  const int lane = tid & 63, wid = tid >> 6;
  const int wr = wid >> 2, wc = wid & 3;            // 2M x 4N waves, 64x64 each
  const int lq = lane & 15, ro = lane >> 4;

  // XCD c owns 8M x 3N rectangle (A 8MB + B 6MB)
  const int c = blockIdx.x & 7, q = blockIdx.x >> 3;      // q: 0..23
  const int by = (c & 1) * 8 + (q & 7);                   // 0..15 (M-tiles of 128)
  const int bx = (c >> 1) * 3 + (q >> 3);                 // 0..11 (N-tiles of 256)
  const int m0 = by * 128, n0 = bx * 256;

  const int R0 = tid >> 3;
  const int g0 = (((tid & 7) ^ (R0 & 7)) << 3);
  const size_t aOff = (size_t)(m0 + R0) * ATT_N + g0;
  size_t bOff[2][2];
#pragma unroll
  for (int h = 0; h < 2; ++h)
#pragma unroll
    for (int r = 0; r < 2; ++r) {
      int rr = min(n0 + h * 128 + r * 64 + R0, HID_D - 1);
      bOff[h][r] = (size_t)rr * ATT_N + g0;
    }

  const int ck0 = ((ro ^ (lq & 7)) << 3);
  const int ck1 = (((4 + ro) ^ (lq & 7)) << 3);

#define OSTG_A(BUF, KT)                                                         \
  { unsigned short* _d = sA + (BUF) * 8192 + wid * 512;                         \
    const unsigned short* _s = att + aOff + (size_t)(KT) * 64;                  \
    gload_lds16(_s, _d); gload_lds16(_s + (size_t)64 * ATT_N, _d + 4096); }
#define OSTG_B(BUF, H, KT)                                                      \
  { unsigned short* _d = sB + ((BUF) * 2 + (H)) * 8192 + wid * 512;             \
    gload_lds16(wo + bOff[H][0] + (KT) * 64, _d);                               \
    gload_lds16(wo + bOff[H][1] + (KT) * 64, _d + 4096); }

  bf16x8 aR[8];
  bf16x8 bR0[4], bR1[4];
  f32x4 acc[4][4] = {};

#define OLDA(BUF)                                                                          \
  { _Pragma("unroll") for (int ii = 0; ii < 4; ++ii) {                                     \
      const int _r = (BUF) * 8192 + (wr * 64 + ii * 16 + lq) * 64;                         \
      aR[ii * 2 + 0] = *(const bf16x8*)&sA[_r + ck0];                                      \
      aR[ii * 2 + 1] = *(const bf16x8*)&sA[_r + ck1]; } }
#define OLDB(BUF, NHF, DST)                                                                \
  { _Pragma("unroll") for (int jj = 0; jj < 2; ++jj) {                                     \
      const int _r = ((BUF) * 2 + (wc >> 1)) * 8192 +                                      \
                     ((wc & 1) * 64 + ((NHF) * 2 + jj) * 16 + lq) * 64;                    \
      DST[jj * 2 + 0] = *(const bf16x8*)&sB[_r + ck0];                                     \
      DST[jj * 2 + 1] = *(const bf16x8*)&sB[_r + ck1]; } }
#define OMFMA(NHF, BREG)                                                                   \
  { _Pragma("unroll") for (int ii = 0; ii < 4; ++ii)                                       \
    _Pragma("unroll") for (int jj = 0; jj < 2; ++jj)                                       \
    _Pragma("unroll") for (int kk = 0; kk < 2; ++kk)                                       \
      acc[ii][(NHF) * 2 + jj] = __builtin_amdgcn_mfma_f32_16x16x32_bf16(                   \
          aR[ii * 2 + kk], BREG[jj * 2 + kk], acc[ii][(NHF) * 2 + jj], 0, 0, 0); }
#define OPH_MID()                                        \
  __builtin_amdgcn_s_barrier();                          \
  asm volatile("s_waitcnt lgkmcnt(0)" ::: "memory");     \
  __builtin_amdgcn_sched_barrier(0);                     \
  __builtin_amdgcn_s_setprio(1)
#define OPH_END()                                        \
  __builtin_amdgcn_s_setprio(0);                         \
  __builtin_amdgcn_s_barrier()

  // prologue: tiles 0 (A-buf0, B-buf0) and 1 (A-buf1, B-buf1)
  OSTG_B(0, 0, 0); OSTG_B(0, 1, 0); OSTG_A(0, 0);
  OSTG_B(1, 0, 1); OSTG_B(1, 1, 1); OSTG_A(1, 1);
  asm volatile("s_waitcnt vmcnt(6)" ::: "memory");
  __builtin_amdgcn_s_barrier();

  const int nt = 64;                                // K = 4096 / 64
  for (int it = 0; it < nt / 2; ++it) {
    const int T = it * 2;
    const bool more = (T + 2 < nt);                 // T+2 and T+3 valid together (nt even)
    const int bb0 = T % 3, bb1 = (T + 1) % 3;
    const int bb2 = (T + 2) % 3, bb3 = (T + 3) % 3;
    // P1: compute tile T, N-half0; stage B(T+2)
    OLDA(T & 1); OLDB(bb0, 0, bR0);
    if (more) { OSTG_B(bb2, 0, T + 2); OSTG_B(bb2, 1, T + 2); }
    OPH_MID(); OMFMA(0, bR0); OPH_END();
    // P2: tile T, N-half1; stage A(T+2) (A-buf T&1 reads done at P1)
    OLDB(bb0, 1, bR1);
    if (more) OSTG_A(T & 1, T + 2);
    OPH_MID(); OMFMA(1, bR1);
    __builtin_amdgcn_s_setprio(0);
    if (more) asm volatile("s_waitcnt vmcnt(6)" ::: "memory");
    else      asm volatile("s_waitcnt vmcnt(0)" ::: "memory");
    __builtin_amdgcn_s_barrier();
    // P3: tile T+1, N-half0; stage B(T+3) into bb3 (== bb0, reads done at P2)
    OLDA((T + 1) & 1); OLDB(bb1, 0, bR0);
    if (more) { OSTG_B(bb3, 0, T + 3); OSTG_B(bb3, 1, T + 3); }
    OPH_MID(); OMFMA(0, bR0); OPH_END();
    // P4: tile T+1, N-half1; stage A(T+3)
    OLDB(bb1, 1, bR1);
    if (more) OSTG_A((T + 1) & 1, T + 3);
    OPH_MID(); OMFMA(1, bR1);
    __builtin_amdgcn_s_setprio(0);
    if (more) asm volatile("s_waitcnt vmcnt(6)" ::: "memory");
    else      asm volatile("s_waitcnt vmcnt(0)" ::: "memory");
    __builtin_amdgcn_s_barrier();
  }
#undef OSTG_A
#undef OSTG_B
#undef OLDA
#undef OLDB
#undef OMFMA
#undef OPH_MID
#undef OPH_END

  // epilogue: out = acc + b_o + x
#pragma unroll
  for (int ii = 0; ii < 4; ++ii) {
    const int gr = m0 + wr * 64 + ii * 16 + ro * 4;
#pragma unroll
    for (int j = 0; j < 4; ++j) {
      const int gc = n0 + wc * 64 + j * 16 + lq;
      if (gc < HID_D) {
        const float bv = b_o[gc];
#pragma unroll
        for (int r = 0; r < 4; ++r) {
          size_t off = (size_t)(gr + r) * HID_D + gc;
          out[off] = acc[ii][j][r] + bv + x[off];
        }
      }
    }
  }
}

// ---------------- fused YaRN RoPE (q,k) + V transpose, reading bf16 qkv ----------------
__global__ __launch_bounds__(256) void ropev_kernel(const unsigned short* __restrict__ qkvb,
                                                    const int* __restrict__ positions,
                                                    unsigned short* __restrict__ qb,
                                                    unsigned short* __restrict__ kb,
                                                    unsigned short* __restrict__ vt) {
  int idx = blockIdx.x * 256 + threadIdx.x;
  if (idx < ROPE_TOT) {
    int d = idx & 31;
    int head = (idx >> 5) % (NH + NKV);
    int t = idx / ((NH + NKV) * 32);
    float pw = (float)d * (1.0f / 32.0f);
    float extrap = expf(-pw * 11.9183905733f);
    float interp = extrap * (1.0f / 32.0f);
    float ramp = fminf(fmaxf(((float)d - 8.0f) * 0.1f, 0.0f), 1.0f);
    float invf = interp * ramp + extrap * (1.0f - ramp);
    float fr = (float)positions[t] * invf;
    float s, c;
    sincosf(fr, &s, &c);
    c *= MSCALE;
    s *= MSCALE;
    if (head < NH) {
      const unsigned short* b = qkvb + (size_t)t * QKV_N + head * HD + d;
      float x1 = bf2f(b[0]), x2 = bf2f(b[32]);
      unsigned short* ob = qb + (size_t)t * ATT_N + head * HD + d;
      ob[0] = f2bf(x1 * c - x2 * s);
      ob[32] = f2bf(x2 * c + x1 * s);
    } else {
      int gk = head - NH;
      const unsigned short* b = qkvb + (size_t)t * QKV_N + NH * HD + gk * HD + d;
      float x1 = bf2f(b[0]), x2 = bf2f(b[32]);
      unsigned short* ob = kb + (size_t)t * (NKV * HD) + gk * HD + d;
      ob[0] = f2bf(x1 * c - x2 * s);
      ob[32] = f2bf(x2 * c + x1 * s);
    }
  } else {
    int i2 = idx - ROPE_TOT;                      // (g*64+d)*2048 + t
    int t = i2 & (T_SEQ - 1);
    int d = (i2 >> 11) & 63;
    int g = i2 >> 17;
    vt[i2] = qkvb[(size_t)t * QKV_N + (NH + NKV) * HD + g * HD + d];
  }
}

// ---------------- sliding-window attention with sinks ----------------
__global__ __launch_bounds__(256) void attn_kernel(const unsigned short* __restrict__ qb,
                                                   const unsigned short* __restrict__ kb,
                                                   const unsigned short* __restrict__ vt,
                                                   const float* __restrict__ sinks,
                                                   unsigned short* __restrict__ att) {
  const int lane = threadIdx.x & 63;
  const int wid = threadIdx.x >> 6;
  const int q0 = blockIdx.x * 16;
  const int h = blockIdx.y * 4 + wid;
  const int g = h >> 3;
  const int lq = lane & 15;
  const int ro = lane >> 4;

  bf16x8 bq0, bq1;
  {
    const unsigned short* qp = qb + (size_t)(q0 + lq) * ATT_N + h * HD + ro * 8;
    bq0 = *(const bf16x8*)qp;
    bq1 = *(const bf16x8*)(qp + 32);
  }
  float m_run = sinks[h];
  float l_run = 1.0f;
  f32x4 o0 = {0.f, 0.f, 0.f, 0.f}, o1 = o0, o2 = o0, o3 = o0;
  const int qg = q0 + lq;
  const int jstart = (q0 >= WIN) ? q0 - WIN : 0;

  for (int jt = jstart; jt <= q0; jt += 32) {
    f32x4 st0 = {0.f, 0.f, 0.f, 0.f}, st1 = st0;
    {
      int kr = jt + ((lq >> 2) << 3) + (lq & 3);
      int kr0 = min(kr, T_SEQ - 1);
      int kr1 = min(kr + 4, T_SEQ - 1);
      const unsigned short* kp0 = kb + (size_t)kr0 * (NKV * HD) + g * HD + ro * 8;
      const unsigned short* kp1 = kb + (size_t)kr1 * (NKV * HD) + g * HD + ro * 8;
      bf16x8 ka0a = *(const bf16x8*)kp0;
      bf16x8 ka0b = *(const bf16x8*)(kp0 + 32);
      bf16x8 ka1a = *(const bf16x8*)kp1;
      bf16x8 ka1b = *(const bf16x8*)(kp1 + 32);
      st0 = __builtin_amdgcn_mfma_f32_16x16x32_bf16(ka0a, bq0, st0, 0, 0, 0);
      st0 = __builtin_amdgcn_mfma_f32_16x16x32_bf16(ka0b, bq1, st0, 0, 0, 0);
      st1 = __builtin_amdgcn_mfma_f32_16x16x32_bf16(ka1a, bq0, st1, 0, 0, 0);
      st1 = __builtin_amdgcn_mfma_f32_16x16x32_bf16(ka1b, bq1, st1, 0, 0, 0);
    }
    float p[8];
    float tmax = -3.0e30f;
#pragma unroll
    for (int r = 0; r < 4; ++r) {
      int jg0 = jt + ro * 8 + r;
      int jg1 = jg0 + 4;
      float s0 = (jg0 <= qg && (qg - jg0) < WIN) ? st0[r] * RSCALE : -3.0e30f;
      float s1 = (jg1 <= qg && (qg - jg1) < WIN) ? st1[r] * RSCALE : -3.0e30f;
      p[r] = s0;
      p[r + 4] = s1;
      tmax = fmaxf(tmax, fmaxf(s0, s1));
    }
    tmax = fmaxf(tmax, __shfl_xor(tmax, 16));
    tmax = fmaxf(tmax, __shfl_xor(tmax, 32));
    float m_new = fmaxf(m_run, tmax);
    float rescale = expf(m_run - m_new);
    float psum = 0.f;
    bf16x8 pa;
#pragma unroll
    for (int jj = 0; jj < 8; ++jj) {
      float pe = expf(p[jj] - m_new);
      psum += pe;
      pa[jj] = (short)f2bf(pe);
    }
    psum += __shfl_xor(psum, 16);
    psum += __shfl_xor(psum, 32);
    l_run = l_run * rescale + psum;
    m_run = m_new;
    f32x4 rs4;
#pragma unroll
    for (int r = 0; r < 4; ++r) rs4[r] = __shfl(rescale, ro * 4 + r);
    o0 *= rs4; o1 *= rs4; o2 *= rs4; o3 *= rs4;
    int tb = jt + ro * 8;
    if (tb > T_SEQ - 8) tb = T_SEQ - 8;
    const unsigned short* vp = vt + (size_t)(g * HD + lq) * T_SEQ + tb;
    bf16x8 v0 = *(const bf16x8*)vp;
    bf16x8 v1 = *(const bf16x8*)(vp + 16 * T_SEQ);
    bf16x8 v2 = *(const bf16x8*)(vp + 32 * T_SEQ);
    bf16x8 v3 = *(const bf16x8*)(vp + 48 * T_SEQ);
    o0 = __builtin_amdgcn_mfma_f32_16x16x32_bf16(pa, v0, o0, 0, 0, 0);
    o1 = __builtin_amdgcn_mfma_f32_16x16x32_bf16(pa, v1, o1, 0, 0, 0);
    o2 = __builtin_amdgcn_mfma_f32_16x16x32_bf16(pa, v2, o2, 0, 0, 0);
    o3 = __builtin_amdgcn_mfma_f32_16x16x32_bf16(pa, v3, o3, 0, 0, 0);
  }

#pragma unroll
  for (int r = 0; r < 4; ++r) {
    float lr = __shfl(l_run, ro * 4 + r);
    float inv = 1.0f / lr;
    int qrow = q0 + ro * 4 + r;
    unsigned short* op = att + (size_t)qrow * ATT_N + h * HD + lq;
    op[0] = f2bf(o0[r] * inv);
    op[16] = f2bf(o1[r] * inv);
    op[32] = f2bf(o2[r] * inv);
    op[48] = f2bf(o3[r] * inv);
  }
}

extern "C" void kernel_launch(void* const* d_in, const int* in_sizes, int n_in,
                              void* d_out, int out_size, void* d_ws, size_t ws_size,
                              hipStream_t stream) {
  const float* x = (const float*)d_in[0];
  const int* pos = (const int*)d_in[1];
  const float* norm_w = (const float*)d_in[2];
  const float* w_qkv = (const float*)d_in[3];
  const float* b_qkv = (const float*)d_in[4];
  const float* w_o = (const float*)d_in[5];
  const float* b_o = (const float*)d_in[6];
  const float* sinks = (const float*)d_in[7];
  float* out = (float*)d_out;

  unsigned short* t_bf = (unsigned short*)d_ws;                        // [2048][2944]
  unsigned short* wq_bf = t_bf + (size_t)T_SEQ * KPAD;                 // [5120][2944]
  unsigned short* wo_bf = wq_bf + (size_t)QKV_N * KPAD;                // [2880][4096]
  unsigned short* qkv_bf = wo_bf + (size_t)HID_D * ATT_N;              // [2048][5120] bf16
  unsigned short* qb = qkv_bf + (size_t)T_SEQ * QKV_N;                 // [2048][4096]
  unsigned short* kb = qb + (size_t)T_SEQ * ATT_N;                     // [2048][512]
  unsigned short* vt = kb + (size_t)T_SEQ * NKV * HD;                  // [8][64][2048]
  unsigned short* att = vt + (size_t)NKV * HD * T_SEQ;                 // [2048][4096]

  // 1. RMSNorm + w_qkv conversion
  pre_kernel<<<3072, 256, 0, stream>>>(x, norm_w, t_bf, w_qkv, wq_bf);
  // 2. QKV GEMM (160 blocks) + w_o conversion (96 blocks)
  qkv_fused_kernel<<<256, 512, 0, stream>>>(t_bf, wq_bf, qkv_bf, b_qkv, w_o, wo_bf);
  // 3. RoPE + V transpose
  ropev_kernel<<<(ROPE_TOT + VT_TOT) / 256, 256, 0, stream>>>(qkv_bf, pos, qb, kb, vt);
  // 4. attention
  attn_kernel<<<dim3(T_SEQ / 16, NH / 4), 256, 0, stream>>>(qb, kb, vt, sinks, att);
  // 5. out projection: full-K 128x256 tiles, direct store with bias + residual
  outproj128_kernel<<<192, 512, 0, stream>>>(att, wo_bf, out, b_o, x);
}